// Round 1
// baseline (248.019 us; speedup 1.0000x reference)
//
#include <hip/hip_runtime.h>

#define NQ 14
#define NSTATES (1 << NQ)   // 16384
#define NB 4
#define THREADS 1024

// LDS bank swizzle: bijective on [0,16384), verified (GF(2) rank analysis) to give
// uniform 2-lanes-per-bank (free) spread for stride-1 passes, all single-qubit pair
// strides k=0..13, and all controlled-gate (two-fixed-bit) subspace enumerations.
__device__ __forceinline__ int swz(int i) {
    return i ^ (((i >> 1) ^ (i >> 3) ^ (i >> 5)) & 31);
}

__global__ __launch_bounds__(THREADS)
void qsim_kernel(const float* __restrict__ inputs,
                 const float* __restrict__ weights,
                 float* __restrict__ out)
{
    __shared__ float2 st[NSTATES];        // 128 KiB state (re,im interleaved)
    __shared__ float lo_tab[128];         // fused-RZ phase tables
    __shared__ float hi_tab[128];
    __shared__ float red[THREADS / 64][NQ];

    const int b = blockIdx.x;
    const int tid = threadIdx.x;

    // ---- init |0...0> (swz(0)==0, so physical-linear zero-fill is correct) ----
#pragma unroll
    for (int j = 0; j < NSTATES / THREADS; ++j) {
        int i = tid + j * THREADS;
        st[i] = make_float2(i == 0 ? 1.0f : 0.0f, 0.0f);
    }
    __syncthreads();

    // ---- single-qubit RY on bit k: [[c,-s],[s,c]] ----
    auto ry_gate = [&](int k, float c, float s) {
#pragma unroll
        for (int j = 0; j < (NSTATES / 2) / THREADS; ++j) {
            int p = tid + j * THREADS;
            int i0 = ((p >> k) << (k + 1)) | (p & ((1 << k) - 1));
            int i1 = i0 | (1 << k);
            int a0 = swz(i0), a1 = swz(i1);
            float2 v0 = st[a0], v1 = st[a1];
            st[a0] = make_float2(c * v0.x - s * v1.x, c * v0.y - s * v1.y);
            st[a1] = make_float2(s * v0.x + c * v1.x, s * v0.y + c * v1.y);
        }
        __syncthreads();
    };

    // ---- CNOT: control bit cb == 1 -> swap target-bit pair ----
    auto cnot_gate = [&](int cb, int tb) {
        int hi = cb > tb ? cb : tb;
        int lo = cb > tb ? tb : cb;
#pragma unroll
        for (int j = 0; j < (NSTATES / 4) / THREADS; ++j) {
            int p = tid + j * THREADS;
            int x = ((p >> lo) << (lo + 1)) | (p & ((1 << lo) - 1));
            x = ((x >> hi) << (hi + 1)) | (x & ((1 << hi) - 1));
            x |= (1 << cb);            // control = 1, target bit = 0
            int y = x | (1 << tb);
            int ax = swz(x), ay = swz(y);
            float2 v0 = st[ax], v1 = st[ay];
            st[ax] = v1;
            st[ay] = v0;
        }
        __syncthreads();
    };

    // ---- controlled-RX: where cb==1 apply [[c,-is],[-is,c]] on tb ----
    auto crx_gate = [&](int cb, int tb, float c, float s) {
        int hi = cb > tb ? cb : tb;
        int lo = cb > tb ? tb : cb;
#pragma unroll
        for (int j = 0; j < (NSTATES / 4) / THREADS; ++j) {
            int p = tid + j * THREADS;
            int x = ((p >> lo) << (lo + 1)) | (p & ((1 << lo) - 1));
            x = ((x >> hi) << (hi + 1)) | (x & ((1 << hi) - 1));
            x |= (1 << cb);
            int y = x | (1 << tb);
            int ax = swz(x), ay = swz(y);
            float2 v0 = st[ax], v1 = st[ay];
            // new0 = c*a0 - i*s*a1 ; new1 = c*a1 - i*s*a0
            st[ax] = make_float2(c * v0.x + s * v1.y, c * v0.y - s * v1.x);
            st[ay] = make_float2(c * v1.x + s * v0.y, c * v1.y - s * v0.x);
        }
        __syncthreads();
    };

    // ---- initial RY encoding layer (per-batch angles) ----
    for (int q = 0; q < NQ; ++q) {
        float th = inputs[b * NQ + q];
        float s, c;
        __sincosf(0.5f * th, &s, &c);
        ry_gate(NQ - 1 - q, c, s);
    }

    // ---- variational blocks ----
    for (int blk = 0; blk < NB; ++blk) {
        const float* wb = weights + blk * 3 * NQ;

        // RY layer (uniform weights)
        for (int q = 0; q < NQ; ++q) {
            float s, c;
            __sincosf(0.5f * wb[q], &s, &c);
            ry_gate(NQ - 1 - q, c, s);
        }
        // CNOT ring, sequential q = 0..13
        for (int q = 0; q < NQ; ++q) {
            int cb = NQ - 1 - q;
            int tb = NQ - 1 - ((q + 1) % NQ);
            cnot_gate(cb, tb);
        }
        // Fused RZ layer: all 14 diagonal gates in ONE pass.
        // phase(i) = sum_q (bit_q ? +th_q/2 : -th_q/2), amplitude *= e^{i*phase}
        if (tid < 128) {
            float lo = 0.f, hi2 = 0.f;
#pragma unroll
            for (int j2 = 0; j2 < 7; ++j2) {
                float hl = 0.5f * wb[NQ + (13 - j2)];      // index bit j2   -> qubit 13-j2
                lo += ((tid >> j2) & 1) ? hl : -hl;
                float hh = 0.5f * wb[NQ + (6 - j2)];       // index bit j2+7 -> qubit 6-j2
                hi2 += ((tid >> j2) & 1) ? hh : -hh;
            }
            lo_tab[tid] = lo;
            hi_tab[tid] = hi2;
        }
        __syncthreads();
#pragma unroll
        for (int j = 0; j < NSTATES / THREADS; ++j) {
            int i = tid + j * THREADS;
            float phi = lo_tab[i & 127] + hi_tab[i >> 7];
            float s, c;
            __sincosf(phi, &s, &c);
            int a = swz(i);
            float2 v = st[a];
            st[a] = make_float2(v.x * c - v.y * s, v.y * c + v.x * s);
        }
        __syncthreads();

        // CRX ring, sequential q = 0..13
        for (int q = 0; q < NQ; ++q) {
            float s, c;
            __sincosf(0.5f * wb[2 * NQ + q], &s, &c);
            int cb = NQ - 1 - q;
            int tb = NQ - 1 - ((q + 1) % NQ);
            crx_gate(cb, tb, c, s);
        }
    }

    // ---- measurement: <Z_q> = P(bit_q=0) - P(bit_q=1) ----
    float acc[NQ];
#pragma unroll
    for (int q = 0; q < NQ; ++q) acc[q] = 0.f;
#pragma unroll
    for (int j = 0; j < NSTATES / THREADS; ++j) {
        int i = tid + j * THREADS;
        float2 v = st[swz(i)];
        float p = v.x * v.x + v.y * v.y;
#pragma unroll
        for (int q = 0; q < NQ; ++q)
            acc[q] += ((i >> (NQ - 1 - q)) & 1) ? -p : p;
    }
#pragma unroll
    for (int q = 0; q < NQ; ++q) {
        float v = acc[q];
        v += __shfl_down(v, 32);
        v += __shfl_down(v, 16);
        v += __shfl_down(v, 8);
        v += __shfl_down(v, 4);
        v += __shfl_down(v, 2);
        v += __shfl_down(v, 1);
        acc[q] = v;
    }
    const int wave = tid >> 6, lane = tid & 63;
    if (lane == 0) {
#pragma unroll
        for (int q = 0; q < NQ; ++q) red[wave][q] = acc[q];
    }
    __syncthreads();
    if (tid < NQ) {
        float v = 0.f;
#pragma unroll
        for (int w = 0; w < THREADS / 64; ++w) v += red[w][tid];
        out[b * NQ + tid] = v;
    }
}

extern "C" void kernel_launch(void* const* d_in, const int* in_sizes, int n_in,
                              void* d_out, int out_size, void* d_ws, size_t ws_size,
                              hipStream_t stream) {
    const float* inputs = (const float*)d_in[0];
    const float* weights = (const float*)d_in[1];
    float* out = (float*)d_out;
    const int B = in_sizes[0] / NQ;   // 256
    qsim_kernel<<<dim3(B), dim3(THREADS), 0, stream>>>(inputs, weights, out);
}

// Round 2
// 150.560 us; speedup vs baseline: 1.6473x; 1.6473x over previous
//
#include <hip/hip_runtime.h>
#include <string.h>

#define NQ 14
#define NST (1 << NQ)      // 16384
#define THREADS 1024

// ---------------- shared descriptor types (host builds, kernel consumes) ----------------
struct PassD {
    unsigned short combo[16];   // PRE-SWIZZLED xor offsets for tile element j
    unsigned short rows[4];     // R row (base-parity mask) per tile bit
    unsigned short widx[4];     // weight index per gate
    unsigned char  pivots[4];   // ascending pivot bit positions for coset spread
    short          rzidx;       // >=0: fold RZ layer (index into rz[]) before gates
    unsigned char  measfold;    // 1: fold measurement after gates, skip store
    unsigned char  type;        // 0 = RY group, 1 = CRX group
    unsigned char  ngates;
    unsigned char  pad;
};
struct RZD  { unsigned short rows_ng[10], widx_ng[10], widx_g[4]; };
struct AllD { PassD pass[32]; RZD rz[4]; unsigned short meas_rows_ng[10]; };

// LDS bank swizzle — GF(2)-linear, swz(0)=0
static inline int h_swz(int i) { return i ^ ((((i >> 1) ^ (i >> 3) ^ (i >> 5))) & 31); }
__device__ __forceinline__ int swz(int i) { return i ^ ((((i >> 1) ^ (i >> 3) ^ (i >> 5))) & 31); }

// ---------------- device kernel ----------------
__global__ __launch_bounds__(THREADS)
void qsim_kernel(const float* __restrict__ inputs,
                 const float* __restrict__ weights,
                 float* __restrict__ out,
                 AllD A)
{
    __shared__ float2 st[NST];          // 128 KiB state
    __shared__ float  tab[256];         // product-state tables (lo:0..127, hi:128..255)
    __shared__ float  red[THREADS / 64][NQ];

    const int b = blockIdx.x;
    const int tid = threadIdx.x;

    // ---- generation pass: init RY(inputs) fused with block0 RY(w) -> product state ----
    if (tid < 256) {
        int half = tid >> 7, t = tid & 127;
        float prod = 1.f;
#pragma unroll
        for (int j = 0; j < 7; ++j) {
            int xb = j + 7 * half;          // state bit
            int q  = 13 - xb;               // qubit
            float a = 0.5f * (inputs[b * NQ + q] + weights[q]);  // RY(a+b) fold
            float s, c; __sincosf(a, &s, &c);
            prod *= ((t >> j) & 1) ? s : c;
        }
        tab[tid] = prod;
    }
    __syncthreads();
#pragma unroll
    for (int j = 0; j < 16; ++j) {
        int x = tid + j * THREADS;
        st[swz(x)] = make_float2(tab[x & 127] * tab[128 + (x >> 7)], 0.f);
    }
    __syncthreads();

    float acc[NQ];
#pragma unroll
    for (int q = 0; q < NQ; ++q) acc[q] = 0.f;

    // ---- 32 fused passes ----
    for (int p = 0; p < 32; ++p) {
        const PassD& P = A.pass[p];

        // coset representative: spread tid over non-pivot bits (pivots ascending)
        int x0 = tid;
#pragma unroll
        for (int i = 0; i < 4; ++i) {
            int pv = P.pivots[i];
            x0 = ((x0 >> pv) << (pv + 1)) | (x0 & ((1 << pv) - 1));
        }
        const int sx0 = swz(x0);

        float2 v[16];
#pragma unroll
        for (int j = 0; j < 16; ++j) v[j] = st[sx0 ^ P.combo[j]];

        if (P.type == 0) {
            // ---- RY group: gate g acts on tile bit g ----
#pragma unroll
            for (int g = 0; g < 4; ++g) if (g < P.ngates) {
                float ang = 0.5f * weights[P.widx[g]];
                float s, c; __sincosf(ang, &s, &c);
                if (__popc(P.rows[g] & x0) & 1) s = -s;   // basis order swapped -> RY(-θ)
#pragma unroll
                for (int j = 0; j < 16; ++j) if (!((j >> g) & 1)) {
                    int j1 = j | (1 << g);
                    float2 a0 = v[j], a1 = v[j1];
                    v[j]  = make_float2(c * a0.x - s * a1.x, c * a0.y - s * a1.y);
                    v[j1] = make_float2(s * a0.x + c * a1.x, s * a0.y + c * a1.y);
                }
            }
        } else {
            // ---- optional fused RZ layer (applies to every amplitude exactly once) ----
            if (P.rzidx >= 0) {
                const RZD& Z = A.rz[P.rzidx];
                float phi0 = 0.f;
#pragma unroll
                for (int t = 0; t < 10; ++t) {
                    float h = 0.5f * weights[Z.widx_ng[t]];
                    phi0 += (__popc(Z.rows_ng[t] & x0) & 1) ? h : -h;
                }
                float e0, e1, e2, e3;
                {
                    float h;
                    h = 0.5f * weights[Z.widx_g[0]]; e0 = (__popc(P.rows[0] & x0) & 1) ? h : -h;
                    h = 0.5f * weights[Z.widx_g[1]]; e1 = (__popc(P.rows[1] & x0) & 1) ? h : -h;
                    h = 0.5f * weights[Z.widx_g[2]]; e2 = (__popc(P.rows[2] & x0) & 1) ? h : -h;
                    h = 0.5f * weights[Z.widx_g[3]]; e3 = (__popc(P.rows[3] & x0) & 1) ? h : -h;
                }
#pragma unroll
                for (int j = 0; j < 16; ++j) {
                    float phi = phi0 + ((j & 1) ? -e0 : e0) + ((j & 2) ? -e1 : e1)
                                     + ((j & 4) ? -e2 : e2) + ((j & 8) ? -e3 : e3);
                    float s, c; __sincosf(phi, &s, &c);
                    float2 a = v[j];
                    v[j] = make_float2(a.x * c - a.y * s, a.y * c + a.x * s);
                }
            }
            // ---- CRX chain: gate g: control = tile bit g, target = tile bit g+1 ----
#pragma unroll
            for (int g = 0; g < 3; ++g) if (g < P.ngates) {
                float ang = 0.5f * weights[P.widx[g]];
                float s, c; __sincosf(ang, &s, &c);
                int bc = __popc(P.rows[g] & x0) & 1;      // control base parity
#pragma unroll
                for (int j = 0; j < 16; ++j) if (!((j >> (g + 1)) & 1)) {
                    int j1 = j | (1 << (g + 1));
                    int on = bc ^ ((j >> g) & 1);          // logical control == 1 ?
                    float ce = on ? c : 1.f, se = on ? s : 0.f;
                    float2 a0 = v[j], a1 = v[j1];
                    // RX: new0 = c*a0 - i s*a1 ; new1 = c*a1 - i s*a0  (symmetric)
                    v[j]  = make_float2(ce * a0.x + se * a1.y, ce * a0.y - se * a1.x);
                    v[j1] = make_float2(ce * a1.x + se * a0.y, ce * a1.y - se * a0.x);
                }
            }
        }

        if (P.measfold) {
            // tile bits 0..3 correspond to qubits {12,13,0,11}; non-group = qubits 1..10
            float psum = 0.f, pg0 = 0.f, pg1 = 0.f, pg2 = 0.f, pg3 = 0.f;
#pragma unroll
            for (int j = 0; j < 16; ++j) {
                float pj = v[j].x * v[j].x + v[j].y * v[j].y;
                psum += pj;
                if (j & 1) pg0 += pj;
                if (j & 2) pg1 += pj;
                if (j & 4) pg2 += pj;
                if (j & 8) pg3 += pj;
            }
            float s0 = (__popc(P.rows[0] & x0) & 1) ? -1.f : 1.f;
            float s1 = (__popc(P.rows[1] & x0) & 1) ? -1.f : 1.f;
            float s2 = (__popc(P.rows[2] & x0) & 1) ? -1.f : 1.f;
            float s3 = (__popc(P.rows[3] & x0) & 1) ? -1.f : 1.f;
            acc[12] += s0 * (psum - 2.f * pg0);
            acc[13] += s1 * (psum - 2.f * pg1);
            acc[0]  += s2 * (psum - 2.f * pg2);
            acc[11] += s3 * (psum - 2.f * pg3);
#pragma unroll
            for (int t = 0; t < 10; ++t) {
                float sg = (__popc(A.meas_rows_ng[t] & x0) & 1) ? -1.f : 1.f;
                acc[1 + t] += sg * psum;
            }
        } else {
#pragma unroll
            for (int j = 0; j < 16; ++j) st[sx0 ^ P.combo[j]] = v[j];
            __syncthreads();
        }
    }

    // ---- block-wide reduction of acc[14] ----
#pragma unroll
    for (int q = 0; q < NQ; ++q) {
        float v2 = acc[q];
        v2 += __shfl_down(v2, 32);
        v2 += __shfl_down(v2, 16);
        v2 += __shfl_down(v2, 8);
        v2 += __shfl_down(v2, 4);
        v2 += __shfl_down(v2, 2);
        v2 += __shfl_down(v2, 1);
        acc[q] = v2;
    }
    const int wave = tid >> 6, lane = tid & 63;
    if (lane == 0) {
#pragma unroll
        for (int q = 0; q < NQ; ++q) red[wave][q] = acc[q];
    }
    __syncthreads();
    if (tid < NQ) {
        float v2 = 0.f;
#pragma unroll
        for (int w = 0; w < THREADS / 64; ++w) v2 += red[w][tid];
        out[b * NQ + tid] = v2;
    }
}

// ---------------- host: build static GF(2) relabeling schedule ----------------
static void build_desc(AllD& A) {
    memset(&A, 0, sizeof(A));
    unsigned short R[NQ], C[NQ];          // rows of R (storage->logical), columns of R^-1
    for (int k = 0; k < NQ; ++k) { R[k] = (unsigned short)(1u << k); C[k] = (unsigned short)(1u << k); }
    int np = 0;

    auto add_pass = [&](int type, int ng, const int tb[4], const int wq[4]) -> PassD& {
        PassD& P = A.pass[np++];
        P.type = (unsigned char)type; P.ngates = (unsigned char)ng;
        P.rzidx = -1; P.measfold = 0;
        unsigned short m[4];
        for (int i = 0; i < 4; ++i) { m[i] = C[tb[i]]; P.rows[i] = R[tb[i]]; P.widx[i] = (unsigned short)wq[i]; }
        for (int j = 0; j < 16; ++j) {
            unsigned short x = 0;
            for (int i = 0; i < 4; ++i) if ((j >> i) & 1) x ^= m[i];
            P.combo[j] = (unsigned short)h_swz(x);        // pre-swizzled
        }
        // Gaussian elimination, highest-bit pivots
        unsigned short red2[4]; int piv[4];
        for (int i = 0; i < 4; ++i) {
            unsigned short v = m[i];
            for (int k2 = 0; k2 < i; ++k2) if ((v >> piv[k2]) & 1) v ^= red2[k2];
            int pp = 13; while (!((v >> pp) & 1)) --pp;
            piv[i] = pp; red2[i] = v;
        }
        for (int a = 0; a < 4; ++a)
            for (int b2 = a + 1; b2 < 4; ++b2)
                if (piv[b2] < piv[a]) { int t = piv[a]; piv[a] = piv[b2]; piv[b2] = t; }
        for (int i = 0; i < 4; ++i) P.pivots[i] = (unsigned char)piv[i];
        return P;
    };
    auto ring = [&]() {   // CNOT ring relabeling: for q=0..13, CNOT(c=13-q, t=13-((q+1)%14))
        for (int q = 0; q < NQ; ++q) {
            int cb = 13 - q, tb = 13 - ((q + 1) % NQ);
            R[tb] = (unsigned short)(R[tb] ^ R[cb]);
            C[cb] = (unsigned short)(C[cb] ^ C[tb]);
        }
    };

    for (int blk = 0; blk < 4; ++blk) {
        if (blk > 0) {
            // RY layer (4 fused passes) under current R
            const int g0[4] = {13, 12, 11, 10}, g1[4] = {9, 8, 7, 6}, g2[4] = {5, 4, 3, 2}, g3[4] = {1, 0, 3, 2};
            int w0[4], w1[4], w2[4], w3[4];
            for (int i = 0; i < 4; ++i) {
                w0[i] = blk * 42 + (13 - g0[i]);
                w1[i] = blk * 42 + (13 - g1[i]);
                w2[i] = blk * 42 + (13 - g2[i]);
            }
            w3[0] = blk * 42 + 12; w3[1] = blk * 42 + 13; w3[2] = 0; w3[3] = 0;
            add_pass(0, 4, g0, w0); add_pass(0, 4, g1, w1);
            add_pass(0, 4, g2, w2); add_pass(0, 2, g3, w3);
        }
        ring();   // CNOT ring is pure relabeling — no data pass
        // CRX ring: 5 fused passes; chained gates at tile-bit pairs (0,1),(1,2),(2,3)
        const int c0[4] = {13, 12, 11, 10}, c1[4] = {10, 9, 8, 7}, c2[4] = {7, 6, 5, 4},
                  c3[4] = {4, 3, 2, 1},     c4[4] = {1, 0, 13, 2};
        auto wcrx = [&](int q) { return blk * 42 + 28 + q; };
        int wq[4];
        wq[0] = wcrx(0); wq[1] = wcrx(1); wq[2] = wcrx(2); wq[3] = 0;
        PassD& P0 = add_pass(1, 3, c0, wq);
        // fold the (diagonal) RZ layer into this first CRX pass
        P0.rzidx = (short)blk;
        RZD& Z = A.rz[blk];
        for (int i = 0; i < 4; ++i) Z.widx_g[i] = (unsigned short)(blk * 42 + 14 + (13 - c0[i]));
        {
            int t = 0;
            for (int q = 4; q < NQ; ++q, ++t) {
                Z.rows_ng[t] = R[13 - q];
                Z.widx_ng[t] = (unsigned short)(blk * 42 + 14 + q);
            }
        }
        wq[0] = wcrx(3); wq[1] = wcrx(4); wq[2] = wcrx(5);  add_pass(1, 3, c1, wq);
        wq[0] = wcrx(6); wq[1] = wcrx(7); wq[2] = wcrx(8);  add_pass(1, 3, c2, wq);
        wq[0] = wcrx(9); wq[1] = wcrx(10); wq[2] = wcrx(11); add_pass(1, 3, c3, wq);
        wq[0] = wcrx(12); wq[1] = wcrx(13); wq[2] = 0;
        PassD& P4 = add_pass(1, 2, c4, wq);
        if (blk == 3) {
            P4.measfold = 1;   // measurement folded; group tile bits {1,0,13,2} = qubits {12,13,0,11}
            for (int t = 0; t < 10; ++t) {
                int q = 1 + t;                     // non-group qubits 1..10
                A.meas_rows_ng[t] = R[13 - q];
            }
        }
    }
}

extern "C" void kernel_launch(void* const* d_in, const int* in_sizes, int n_in,
                              void* d_out, int out_size, void* d_ws, size_t ws_size,
                              hipStream_t stream) {
    const float* inputs  = (const float*)d_in[0];
    const float* weights = (const float*)d_in[1];
    float* out = (float*)d_out;
    const int B = in_sizes[0] / NQ;   // 256

    AllD A;
    build_desc(A);
    static_assert(sizeof(AllD) <= 3072, "kernarg too big");

    qsim_kernel<<<dim3(B), dim3(THREADS), 0, stream>>>(inputs, weights, out, A);
}

// Round 3
// 70.642 us; speedup vs baseline: 3.5109x; 2.1313x over previous
//
#include <hip/hip_runtime.h>
#include <utility>

#define NQ 14
#define NST (1 << NQ)      // 16384
#define THREADS 1024

// ---------------- compile-time schedule ----------------
struct PassD {
    unsigned short combo[16];   // pre-swizzled xor offsets (element units)
    unsigned short rows[4];     // R row (base-parity mask) per tile bit
    unsigned short widx[4];     // weight index per gate
    unsigned char  pivots[4];   // ascending pivot bits for coset spread
    short          rzidx;       // >=0: fold RZ layer before gates
    unsigned char  measfold;    // 1: fold measurement, skip store
    unsigned char  type;        // 0 = RY group, 1 = CRX group
    unsigned char  ngates;
};
struct RZD  { unsigned short rows_ng[10]; unsigned short widx_ng[10]; unsigned short widx_g[4]; };
struct AllD { PassD pass[32]; RZD rz[4]; unsigned short meas_rows_ng[10]; int npass; };

__host__ __device__ constexpr int swz(int i) { return i ^ ((((i >> 1) ^ (i >> 3) ^ (i >> 5))) & 31); }

constexpr void add_pass(AllD& A, int& np, const unsigned short* R, const unsigned short* C,
                        int type, int ng, const int* tb, const int* wq)
{
    PassD& P = A.pass[np++];
    P.type = (unsigned char)type; P.ngates = (unsigned char)ng;
    P.rzidx = -1; P.measfold = 0;
    unsigned short m[4] = {};
    for (int i = 0; i < 4; ++i) {
        m[i] = C[tb[i]];
        P.rows[i] = R[tb[i]];
        P.widx[i] = (unsigned short)wq[i];
    }
    for (int j = 0; j < 16; ++j) {
        unsigned short x = 0;
        for (int i = 0; i < 4; ++i) if ((j >> i) & 1) x = (unsigned short)(x ^ m[i]);
        P.combo[j] = (unsigned short)swz(x);
    }
    unsigned short red2[4] = {}; int piv[4] = {};
    for (int i = 0; i < 4; ++i) {
        unsigned short v = m[i];
        for (int k = 0; k < i; ++k) if ((v >> piv[k]) & 1) v = (unsigned short)(v ^ red2[k]);
        int pp = 13; while (!((v >> pp) & 1)) --pp;
        piv[i] = pp; red2[i] = v;
    }
    for (int a = 0; a < 4; ++a)
        for (int b = a + 1; b < 4; ++b)
            if (piv[b] < piv[a]) { int t = piv[a]; piv[a] = piv[b]; piv[b] = t; }
    for (int i = 0; i < 4; ++i) P.pivots[i] = (unsigned char)piv[i];
}

constexpr void ring(unsigned short* R, unsigned short* C) {
    for (int q = 0; q < NQ; ++q) {
        int cb = 13 - q, tb = 13 - ((q + 1) % NQ);
        R[tb] = (unsigned short)(R[tb] ^ R[cb]);
        C[cb] = (unsigned short)(C[cb] ^ C[tb]);
    }
}

constexpr AllD build_desc() {
    AllD A{};
    unsigned short R[NQ] = {}, C[NQ] = {};
    for (int k = 0; k < NQ; ++k) { R[k] = (unsigned short)(1u << k); C[k] = (unsigned short)(1u << k); }
    int np = 0;
    for (int blk = 0; blk < 4; ++blk) {
        if (blk > 0) {
            const int g0[4] = {13,12,11,10}, g1[4] = {9,8,7,6}, g2[4] = {5,4,3,2}, g3[4] = {1,0,3,2};
            int w0[4] = {}, w1[4] = {}, w2[4] = {}, w3[4] = {};
            for (int i = 0; i < 4; ++i) {
                w0[i] = blk*42 + (13 - g0[i]);
                w1[i] = blk*42 + (13 - g1[i]);
                w2[i] = blk*42 + (13 - g2[i]);
            }
            w3[0] = blk*42 + 12; w3[1] = blk*42 + 13; w3[2] = 0; w3[3] = 0;
            add_pass(A,np,R,C,0,4,g0,w0); add_pass(A,np,R,C,0,4,g1,w1);
            add_pass(A,np,R,C,0,4,g2,w2); add_pass(A,np,R,C,0,2,g3,w3);
        }
        ring(R,C);   // CNOT ring = pure relabeling
        const int c0[4] = {13,12,11,10}, c1[4] = {10,9,8,7}, c2[4] = {7,6,5,4},
                  c3[4] = {4,3,2,1},     c4[4] = {1,0,13,2};
        int wq[4] = {};
        wq[0] = blk*42+28+0; wq[1] = blk*42+28+1; wq[2] = blk*42+28+2; wq[3] = 0;
        add_pass(A,np,R,C,1,3,c0,wq);
        A.pass[np-1].rzidx = (short)blk;
        RZD& Z = A.rz[blk];
        for (int i = 0; i < 4; ++i) Z.widx_g[i] = (unsigned short)(blk*42 + 14 + (13 - c0[i]));
        {
            int t = 0;
            for (int q = 4; q < NQ; ++q, ++t) {
                Z.rows_ng[t] = R[13 - q];
                Z.widx_ng[t] = (unsigned short)(blk*42 + 14 + q);
            }
        }
        wq[0] = blk*42+28+3;  wq[1] = blk*42+28+4;  wq[2] = blk*42+28+5;  add_pass(A,np,R,C,1,3,c1,wq);
        wq[0] = blk*42+28+6;  wq[1] = blk*42+28+7;  wq[2] = blk*42+28+8;  add_pass(A,np,R,C,1,3,c2,wq);
        wq[0] = blk*42+28+9;  wq[1] = blk*42+28+10; wq[2] = blk*42+28+11; add_pass(A,np,R,C,1,3,c3,wq);
        wq[0] = blk*42+28+12; wq[1] = blk*42+28+13; wq[2] = 0;            add_pass(A,np,R,C,1,2,c4,wq);
        if (blk == 3) {
            A.pass[np-1].measfold = 1;
            for (int t = 0; t < 10; ++t) A.meas_rows_ng[t] = R[13 - (1 + t)];
        }
    }
    A.npass = np;
    return A;
}

constexpr AllD A = build_desc();
static_assert(A.npass == 32, "expected 32 passes");

// spread masks: insert zero bits at the 4 (ascending) pivot positions
struct Spread { unsigned m0, m1, m2, m3, m4; };
constexpr Spread make_spread(const PassD& P) {
    unsigned p0 = P.pivots[0], p1 = P.pivots[1], p2 = P.pivots[2], p3 = P.pivots[3];
    Spread S{};
    S.m0 = (1u << p0) - 1;
    S.m1 = ((1u << p1) - 1) & ~((1u << (p0 + 1)) - 1);
    S.m2 = ((1u << p2) - 1) & ~((1u << (p1 + 1)) - 1);
    S.m3 = ((1u << p3) - 1) & ~((1u << (p2 + 1)) - 1);
    S.m4 = ((1u << NQ) - 1) & ~((1u << (p3 + 1)) - 1);
    return S;
}

// ---------------- per-pass device code (fully constant-folded) ----------------
template<int P>
__device__ __forceinline__ void run_pass(float2* st, float (*tabG)[4][2], float (*tabRZ)[14],
                                         int tid, float* acc)
{
    constexpr PassD Pd = A.pass[P];
    constexpr Spread S = make_spread(Pd);

    const int x0 = (tid & (int)S.m0) | ((tid << 1) & (int)S.m1) | ((tid << 2) & (int)S.m2)
                 | ((tid << 3) & (int)S.m3) | ((tid << 4) & (int)S.m4);
    char* stb = (char*)st;
    const int base = swz(x0) << 3;

    float2 v[16];
#pragma unroll
    for (int j = 0; j < 16; ++j)
        v[j] = *(const float2*)(stb + (base ^ (Pd.combo[j] << 3)));

    if constexpr (Pd.type == 0) {
        // ---- RY group ----
#pragma unroll
        for (int g = 0; g < Pd.ngates; ++g) {
            float c = tabG[P][g][0], s0 = tabG[P][g][1];
            float s = (__popc(x0 & Pd.rows[g]) & 1) ? -s0 : s0;
#pragma unroll
            for (int j = 0; j < 16; ++j) if (!((j >> g) & 1)) {
                int j1 = j | (1 << g);
                float2 a0 = v[j], a1 = v[j1];
                v[j]  = make_float2(c * a0.x - s * a1.x, c * a0.y - s * a1.y);
                v[j1] = make_float2(s * a0.x + c * a1.x, s * a0.y + c * a1.y);
            }
        }
    } else {
        // ---- optional fused RZ layer ----
        if constexpr (Pd.rzidx >= 0) {
            constexpr RZD Z = A.rz[Pd.rzidx];
            float phi0 = 0.f;
#pragma unroll
            for (int t = 0; t < 10; ++t) {
                float h = tabRZ[Pd.rzidx][t];
                phi0 += (__popc(Z.rows_ng[t] & x0) & 1) ? h : -h;
            }
            float e0 = (__popc(Pd.rows[0] & x0) & 1) ? tabRZ[Pd.rzidx][10] : -tabRZ[Pd.rzidx][10];
            float e1 = (__popc(Pd.rows[1] & x0) & 1) ? tabRZ[Pd.rzidx][11] : -tabRZ[Pd.rzidx][11];
            float e2 = (__popc(Pd.rows[2] & x0) & 1) ? tabRZ[Pd.rzidx][12] : -tabRZ[Pd.rzidx][12];
            float e3 = (__popc(Pd.rows[3] & x0) & 1) ? tabRZ[Pd.rzidx][13] : -tabRZ[Pd.rzidx][13];
#pragma unroll
            for (int j = 0; j < 16; ++j) {
                float phi = phi0 + ((j & 1) ? -e0 : e0) + ((j & 2) ? -e1 : e1)
                                 + ((j & 4) ? -e2 : e2) + ((j & 8) ? -e3 : e3);
                float s, c; __sincosf(phi, &s, &c);
                float2 a = v[j];
                v[j] = make_float2(a.x * c - a.y * s, a.y * c + a.x * s);
            }
        }
        // ---- CRX chain: gate g: control = tile bit g, target = tile bit g+1 ----
#pragma unroll
        for (int g = 0; g < Pd.ngates; ++g) {
            float c = tabG[P][g][0], s = tabG[P][g][1];
            int bc = __popc(Pd.rows[g] & x0) & 1;
#pragma unroll
            for (int j = 0; j < 16; ++j) if (!((j >> (g + 1)) & 1)) {
                int j1 = j | (1 << (g + 1));
                int on = bc ^ ((j >> g) & 1);
                float ce = on ? c : 1.f, se = on ? s : 0.f;
                float2 a0 = v[j], a1 = v[j1];
                v[j]  = make_float2(ce * a0.x + se * a1.y, ce * a0.y - se * a1.x);
                v[j1] = make_float2(ce * a1.x + se * a0.y, ce * a1.y - se * a0.x);
            }
        }
    }

    if constexpr (Pd.measfold != 0) {
        float psum = 0.f, pg0 = 0.f, pg1 = 0.f, pg2 = 0.f, pg3 = 0.f;
#pragma unroll
        for (int j = 0; j < 16; ++j) {
            float pj = v[j].x * v[j].x + v[j].y * v[j].y;
            psum += pj;
            if (j & 1) pg0 += pj;
            if (j & 2) pg1 += pj;
            if (j & 4) pg2 += pj;
            if (j & 8) pg3 += pj;
        }
        float s0 = (__popc(Pd.rows[0] & x0) & 1) ? -1.f : 1.f;
        float s1 = (__popc(Pd.rows[1] & x0) & 1) ? -1.f : 1.f;
        float s2 = (__popc(Pd.rows[2] & x0) & 1) ? -1.f : 1.f;
        float s3 = (__popc(Pd.rows[3] & x0) & 1) ? -1.f : 1.f;
        acc[12] += s0 * (psum - 2.f * pg0);
        acc[13] += s1 * (psum - 2.f * pg1);
        acc[0]  += s2 * (psum - 2.f * pg2);
        acc[11] += s3 * (psum - 2.f * pg3);
#pragma unroll
        for (int t = 0; t < 10; ++t) {
            float sg = (__popc(A.meas_rows_ng[t] & x0) & 1) ? -1.f : 1.f;
            acc[1 + t] += sg * psum;
        }
    } else {
#pragma unroll
        for (int j = 0; j < 16; ++j)
            *(float2*)(stb + (base ^ (Pd.combo[j] << 3))) = v[j];
        __syncthreads();
    }
}

template<int... I>
__device__ __forceinline__ void run_all(std::integer_sequence<int, I...>,
                                        float2* st, float (*tabG)[4][2], float (*tabRZ)[14],
                                        int tid, float* acc)
{
    (run_pass<I>(st, tabG, tabRZ, tid, acc), ...);
}

// ---------------- main kernel ----------------
__global__ __launch_bounds__(THREADS)
void qsim_kernel(const float* __restrict__ inputs,
                 const float* __restrict__ weights,
                 float* __restrict__ out)
{
    __shared__ float2 st[NST];           // 128 KiB state
    __shared__ float  tab[256];          // product-state init tables
    __shared__ float  tabG[32][4][2];    // uniform gate (c,s) per pass/gate
    __shared__ float  tabRZ[4][14];      // RZ half-angles per block
    __shared__ float  red[THREADS / 64][NQ];

    const int b = blockIdx.x;
    const int tid = threadIdx.x;

    // ---- build trig + product tables (disjoint thread ranges) ----
    if (tid < 128) {
        int p = tid >> 2, g = tid & 3;
        float w = weights[A.pass[p].widx[g]];
        float s, c; __sincosf(0.5f * w, &s, &c);
        tabG[p][g][0] = c; tabG[p][g][1] = s;
    } else if (tid < 128 + 56) {
        int idx = tid - 128;
        int blk = idx / 14, k = idx - blk * 14;
        unsigned wi = (k < 10) ? A.rz[blk].widx_ng[k] : A.rz[blk].widx_g[k - 10];
        tabRZ[blk][k] = 0.5f * weights[wi];
    } else if (tid >= 256 && tid < 512) {
        int t = tid - 256;
        int half = t >> 7, tt = t & 127;
        float prod = 1.f;
#pragma unroll
        for (int j = 0; j < 7; ++j) {
            int xb = j + 7 * half;
            int q  = 13 - xb;
            float a = 0.5f * (inputs[b * NQ + q] + weights[q]);   // init RY ∘ blk0 RY fold
            float s, c; __sincosf(a, &s, &c);
            prod *= ((tt >> j) & 1) ? s : c;
        }
        tab[t] = prod;
    }
    __syncthreads();

    // ---- write product state ----
#pragma unroll
    for (int j = 0; j < 16; ++j) {
        int x = tid + j * THREADS;
        st[swz(x)] = make_float2(tab[x & 127] * tab[128 + (x >> 7)], 0.f);
    }
    __syncthreads();

    float acc[NQ];
#pragma unroll
    for (int q = 0; q < NQ; ++q) acc[q] = 0.f;

    run_all(std::make_integer_sequence<int, 32>{}, st, tabG, tabRZ, tid, acc);

    // ---- block-wide reduction ----
#pragma unroll
    for (int q = 0; q < NQ; ++q) {
        float v2 = acc[q];
        v2 += __shfl_down(v2, 32);
        v2 += __shfl_down(v2, 16);
        v2 += __shfl_down(v2, 8);
        v2 += __shfl_down(v2, 4);
        v2 += __shfl_down(v2, 2);
        v2 += __shfl_down(v2, 1);
        acc[q] = v2;
    }
    const int wave = tid >> 6, lane = tid & 63;
    if (lane == 0) {
#pragma unroll
        for (int q = 0; q < NQ; ++q) red[wave][q] = acc[q];
    }
    __syncthreads();
    if (tid < NQ) {
        float v2 = 0.f;
#pragma unroll
        for (int w = 0; w < THREADS / 64; ++w) v2 += red[w][tid];
        out[b * NQ + tid] = v2;
    }
}

extern "C" void kernel_launch(void* const* d_in, const int* in_sizes, int n_in,
                              void* d_out, int out_size, void* d_ws, size_t ws_size,
                              hipStream_t stream) {
    const float* inputs  = (const float*)d_in[0];
    const float* weights = (const float*)d_in[1];
    float* out = (float*)d_out;
    const int B = in_sizes[0] / NQ;   // 256
    qsim_kernel<<<dim3(B), dim3(THREADS), 0, stream>>>(inputs, weights, out);
}

// Round 4
// 60.439 us; speedup vs baseline: 4.1036x; 1.1688x over previous
//
#include <hip/hip_runtime.h>
#include <utility>

#define NQ 14
#define NST (1 << NQ)      // 16384
#define THREADS 1024

// ---------------- compile-time schedule ----------------
struct PassD {
    unsigned short combo[16];   // pre-swizzled xor offsets (element units)
    unsigned short rows[4];     // R row (base-parity mask) per tile bit
    unsigned char  pivots[4];   // ascending pivot bits for coset spread
    unsigned short crx_widx[3]; // CRX gate weight indices (chain at tile bits g,g+1)
    unsigned short ry_widx[3];  // folded next-block RY weight indices
    unsigned char  ry_tb[3];    // tile bit each folded RY acts on
    unsigned char  ncrx;        // 2 or 3
    unsigned char  nry;         // 0..3
    short          rzidx;       // >=0: fold RZ layer before CRX chain
    unsigned char  measfold;    // 1: fold measurement, skip store
};
struct RZD  { unsigned short rows_ng[10]; unsigned short widx_ng[10]; unsigned short widx_g[4]; };
struct AllD { PassD pass[20]; RZD rz[4]; unsigned short meas_rows_ng[10]; int npass; };

__host__ __device__ constexpr int swz(int i) { return i ^ ((((i >> 1) ^ (i >> 3) ^ (i >> 5))) & 31); }

constexpr void fill_geom(PassD& P, const unsigned short* R, const unsigned short* C, const int* tb)
{
    unsigned short m[4] = {};
    for (int i = 0; i < 4; ++i) { m[i] = C[tb[i]]; P.rows[i] = R[tb[i]]; }
    for (int j = 0; j < 16; ++j) {
        unsigned short x = 0;
        for (int i = 0; i < 4; ++i) if ((j >> i) & 1) x = (unsigned short)(x ^ m[i]);
        P.combo[j] = (unsigned short)swz(x);
    }
    unsigned short red2[4] = {}; int piv[4] = {};
    for (int i = 0; i < 4; ++i) {
        unsigned short v = m[i];
        for (int k = 0; k < i; ++k) if ((v >> piv[k]) & 1) v = (unsigned short)(v ^ red2[k]);
        int pp = 13; while (!((v >> pp) & 1)) --pp;
        piv[i] = pp; red2[i] = v;
    }
    for (int a = 0; a < 4; ++a)
        for (int b = a + 1; b < 4; ++b)
            if (piv[b] < piv[a]) { int t = piv[a]; piv[a] = piv[b]; piv[b] = t; }
    for (int i = 0; i < 4; ++i) P.pivots[i] = (unsigned char)piv[i];
}

constexpr void ring(unsigned short* R, unsigned short* C) {
    for (int q = 0; q < NQ; ++q) {
        int cb = 13 - q, tb = 13 - ((q + 1) % NQ);
        R[tb] = (unsigned short)(R[tb] ^ R[cb]);
        C[cb] = (unsigned short)(C[cb] ^ C[tb]);
    }
}

constexpr AllD build_desc() {
    AllD A{};
    unsigned short R[NQ] = {}, C[NQ] = {};
    for (int k = 0; k < NQ; ++k) { R[k] = (unsigned short)(1u << k); C[k] = (unsigned short)(1u << k); }
    int np = 0;
    // CRX chain passes: tiles (state bits), first chain-gate idx, gate counts,
    // folded-RY state bits (bits whose ring gates complete in this pass).
    const int tiles[5][4] = {{13,12,11,10},{10,9,8,7},{7,6,5,4},{4,3,2,1},{1,0,13,2}};
    const int gfirst[5]   = {0, 3, 6, 9, 12};
    const int ngate[5]    = {3, 3, 3, 3, 2};
    const int rybits[5][3]= {{11,12,0},{10,9,8},{7,6,5},{4,3,2},{13,1,0}};
    const int nryp[5]     = {2, 3, 3, 3, 3};

    for (int blk = 0; blk < 4; ++blk) {
        ring(R, C);   // CNOT ring = pure relabeling
        for (int pi = 0; pi < 5; ++pi) {
            PassD& P = A.pass[np];
            fill_geom(P, R, C, tiles[pi]);
            P.ncrx = (unsigned char)ngate[pi];
            for (int g = 0; g < 3; ++g)
                P.crx_widx[g] = (unsigned short)((g < ngate[pi]) ? blk*42 + 28 + gfirst[pi] + g : 0);
            if (blk < 3) {
                P.nry = (unsigned char)nryp[pi];
                for (int g = 0; g < 3; ++g) {
                    if (g < nryp[pi]) {
                        int k = rybits[pi][g];                       // state bit
                        P.ry_widx[g] = (unsigned short)((blk + 1)*42 + (13 - k));
                        int t = 0;
                        for (int i = 0; i < 4; ++i) if (tiles[pi][i] == k) t = i;
                        P.ry_tb[g] = (unsigned char)t;
                    } else { P.ry_widx[g] = 0; P.ry_tb[g] = 0; }
                }
            } else { P.nry = 0; for (int g = 0; g < 3; ++g) { P.ry_widx[g] = 0; P.ry_tb[g] = 0; } }
            P.rzidx = (short)((pi == 0) ? blk : -1);
            P.measfold = (unsigned char)((blk == 3 && pi == 4) ? 1 : 0);
            if (pi == 0) {
                RZD& Z = A.rz[blk];
                for (int i = 0; i < 4; ++i)
                    Z.widx_g[i] = (unsigned short)(blk*42 + 14 + (13 - tiles[0][i]));
                int t = 0;
                for (int q = 4; q < NQ; ++q, ++t) {
                    Z.rows_ng[t] = R[13 - q];
                    Z.widx_ng[t] = (unsigned short)(blk*42 + 14 + q);
                }
            }
            ++np;
        }
        if (blk == 3)
            for (int t = 0; t < 10; ++t) A.meas_rows_ng[t] = R[13 - (1 + t)];
    }
    A.npass = np;
    return A;
}

constexpr AllD A = build_desc();
static_assert(A.npass == 20, "expected 20 passes");

// flat gate-weight-index table for the trig-table setup (slots 0-2 CRX, 3-5 RY)
struct GWT { unsigned short w[20][6]; };
constexpr GWT build_gwt() {
    GWT g{};
    for (int p = 0; p < 20; ++p) {
        for (int s = 0; s < 3; ++s) g.w[p][s]     = A.pass[p].crx_widx[s];
        for (int s = 0; s < 3; ++s) g.w[p][3 + s] = A.pass[p].ry_widx[s];
    }
    return g;
}
constexpr GWT GW = build_gwt();

// spread masks: insert zero bits at the 4 (ascending) pivot positions
struct Spread { unsigned m0, m1, m2, m3, m4; };
constexpr Spread make_spread(const PassD& P) {
    unsigned p0 = P.pivots[0], p1 = P.pivots[1], p2 = P.pivots[2], p3 = P.pivots[3];
    Spread S{};
    S.m0 = (1u << p0) - 1;
    S.m1 = ((1u << p1) - 1) & ~((1u << (p0 + 1)) - 1);
    S.m2 = ((1u << p2) - 1) & ~((1u << (p1 + 1)) - 1);
    S.m3 = ((1u << p3) - 1) & ~((1u << (p2 + 1)) - 1);
    S.m4 = ((1u << NQ) - 1) & ~((1u << (p3 + 1)) - 1);
    return S;
}

// ---------------- per-pass device code (fully constant-folded) ----------------
template<int Pi>
__device__ __forceinline__ void run_pass(float2* st, float (*tabG)[6][2], float (*tabRZ)[14],
                                         int tid, float* acc)
{
    constexpr PassD Pd = A.pass[Pi];
    constexpr Spread S = make_spread(Pd);

    const int x0 = (tid & (int)S.m0) | ((tid << 1) & (int)S.m1) | ((tid << 2) & (int)S.m2)
                 | ((tid << 3) & (int)S.m3) | ((tid << 4) & (int)S.m4);
    char* stb = (char*)st;
    const int base = swz(x0) << 3;

    float2 v[16];
#pragma unroll
    for (int j = 0; j < 16; ++j)
        v[j] = *(const float2*)(stb + (base ^ (Pd.combo[j] << 3)));

    // ---- fused RZ layer (first pass of each block; before the CRX chain) ----
    if constexpr (Pd.rzidx >= 0) {
        constexpr RZD Z = A.rz[Pd.rzidx];
        float phi0 = 0.f;
#pragma unroll
        for (int t = 0; t < 10; ++t) {
            float h = tabRZ[Pd.rzidx][t];
            phi0 += (__popc(Z.rows_ng[t] & x0) & 1) ? h : -h;
        }
        float e0 = (__popc(Pd.rows[0] & x0) & 1) ? tabRZ[Pd.rzidx][10] : -tabRZ[Pd.rzidx][10];
        float e1 = (__popc(Pd.rows[1] & x0) & 1) ? tabRZ[Pd.rzidx][11] : -tabRZ[Pd.rzidx][11];
        float e2 = (__popc(Pd.rows[2] & x0) & 1) ? tabRZ[Pd.rzidx][12] : -tabRZ[Pd.rzidx][12];
        float e3 = (__popc(Pd.rows[3] & x0) & 1) ? tabRZ[Pd.rzidx][13] : -tabRZ[Pd.rzidx][13];
#pragma unroll
        for (int j = 0; j < 16; ++j) {
            float phi = phi0 + ((j & 1) ? -e0 : e0) + ((j & 2) ? -e1 : e1)
                             + ((j & 4) ? -e2 : e2) + ((j & 8) ? -e3 : e3);
            float s, c; __sincosf(phi, &s, &c);
            float2 a = v[j];
            v[j] = make_float2(a.x * c - a.y * s, a.y * c + a.x * s);
        }
    }

    // ---- CRX chain: gate g: control = tile bit g, target = tile bit g+1 ----
#pragma unroll
    for (int g = 0; g < Pd.ncrx; ++g) {
        float c = tabG[Pi][g][0], s = tabG[Pi][g][1];
        int bc = __popc(Pd.rows[g] & x0) & 1;
        // two (ce,se) variants, chosen per element by compile-time j-bit g
        float c0 = bc ? c : 1.f, s0 = bc ? s : 0.f;   // logical ctrl for jg==0
        float c1 = bc ? 1.f : c, s1 = bc ? 0.f : s;   // logical ctrl for jg==1
#pragma unroll
        for (int j = 0; j < 16; ++j) if (!((j >> (g + 1)) & 1)) {
            int j1 = j | (1 << (g + 1));
            float ce = ((j >> g) & 1) ? c1 : c0;
            float se = ((j >> g) & 1) ? s1 : s0;
            float2 a0 = v[j], a1 = v[j1];
            v[j]  = make_float2(ce * a0.x + se * a1.y, ce * a0.y - se * a1.x);
            v[j1] = make_float2(ce * a1.x + se * a0.y, ce * a1.y - se * a0.x);
        }
    }

    // ---- folded next-block RY gates (bits whose ring gates are complete) ----
#pragma unroll
    for (int g = 0; g < Pd.nry; ++g) {
        int t = Pd.ry_tb[g];   // compile-time after unroll
        float c = tabG[Pi][3 + g][0], s0 = tabG[Pi][3 + g][1];
        float s = (__popc(Pd.rows[t] & x0) & 1) ? -s0 : s0;
#pragma unroll
        for (int j = 0; j < 16; ++j) if (!((j >> t) & 1)) {
            int j1 = j | (1 << t);
            float2 a0 = v[j], a1 = v[j1];
            v[j]  = make_float2(c * a0.x - s * a1.x, c * a0.y - s * a1.y);
            v[j1] = make_float2(s * a0.x + c * a1.x, s * a0.y + c * a1.y);
        }
    }

    if constexpr (Pd.measfold != 0) {
        float psum = 0.f, pg0 = 0.f, pg1 = 0.f, pg2 = 0.f, pg3 = 0.f;
#pragma unroll
        for (int j = 0; j < 16; ++j) {
            float pj = v[j].x * v[j].x + v[j].y * v[j].y;
            psum += pj;
            if (j & 1) pg0 += pj;
            if (j & 2) pg1 += pj;
            if (j & 4) pg2 += pj;
            if (j & 8) pg3 += pj;
        }
        float s0 = (__popc(Pd.rows[0] & x0) & 1) ? -1.f : 1.f;
        float s1 = (__popc(Pd.rows[1] & x0) & 1) ? -1.f : 1.f;
        float s2 = (__popc(Pd.rows[2] & x0) & 1) ? -1.f : 1.f;
        float s3 = (__popc(Pd.rows[3] & x0) & 1) ? -1.f : 1.f;
        // tile state bits {1,0,13,2} = JAX qubits {12,13,0,11}
        acc[12] += s0 * (psum - 2.f * pg0);
        acc[13] += s1 * (psum - 2.f * pg1);
        acc[0]  += s2 * (psum - 2.f * pg2);
        acc[11] += s3 * (psum - 2.f * pg3);
#pragma unroll
        for (int t = 0; t < 10; ++t) {
            float sg = (__popc(A.meas_rows_ng[t] & x0) & 1) ? -1.f : 1.f;
            acc[1 + t] += sg * psum;
        }
    } else {
#pragma unroll
        for (int j = 0; j < 16; ++j)
            *(float2*)(stb + (base ^ (Pd.combo[j] << 3))) = v[j];
        __syncthreads();
    }
}

template<int... I>
__device__ __forceinline__ void run_all(std::integer_sequence<int, I...>,
                                        float2* st, float (*tabG)[6][2], float (*tabRZ)[14],
                                        int tid, float* acc)
{
    (run_pass<I>(st, tabG, tabRZ, tid, acc), ...);
}

// ---------------- main kernel ----------------
__global__ __launch_bounds__(THREADS)
void qsim_kernel(const float* __restrict__ inputs,
                 const float* __restrict__ weights,
                 float* __restrict__ out)
{
    __shared__ float2 st[NST];           // 128 KiB state
    __shared__ float  tab[256];          // product-state init tables
    __shared__ float  tabG[20][6][2];    // uniform gate (c,s) per pass/slot
    __shared__ float  tabRZ[4][14];      // RZ half-angles per block
    __shared__ float  red[THREADS / 64][NQ];

    const int b = blockIdx.x;
    const int tid = threadIdx.x;

    // ---- build trig + product tables (disjoint thread ranges) ----
    if (tid < 120) {
        int p = tid / 6, sl = tid - p * 6;
        float w = weights[GW.w[p][sl]];
        float s, c; __sincosf(0.5f * w, &s, &c);
        tabG[p][sl][0] = c; tabG[p][sl][1] = s;
    } else if (tid >= 128 && tid < 128 + 56) {
        int idx = tid - 128;
        int blk = idx / 14, k = idx - blk * 14;
        unsigned wi = (k < 10) ? A.rz[blk].widx_ng[k] : A.rz[blk].widx_g[k - 10];
        tabRZ[blk][k] = 0.5f * weights[wi];
    } else if (tid >= 256 && tid < 512) {
        int t = tid - 256;
        int half = t >> 7, tt = t & 127;
        float prod = 1.f;
#pragma unroll
        for (int j = 0; j < 7; ++j) {
            int xb = j + 7 * half;
            int q  = 13 - xb;
            float a = 0.5f * (inputs[b * NQ + q] + weights[q]);   // init RY ∘ blk0 RY fold
            float s, c; __sincosf(a, &s, &c);
            prod *= ((tt >> j) & 1) ? s : c;
        }
        tab[t] = prod;
    }
    __syncthreads();

    // ---- write product state ----
#pragma unroll
    for (int j = 0; j < 16; ++j) {
        int x = tid + j * THREADS;
        st[swz(x)] = make_float2(tab[x & 127] * tab[128 + (x >> 7)], 0.f);
    }
    __syncthreads();

    float acc[NQ];
#pragma unroll
    for (int q = 0; q < NQ; ++q) acc[q] = 0.f;

    run_all(std::make_integer_sequence<int, 20>{}, st, tabG, tabRZ, tid, acc);

    // ---- block-wide reduction ----
#pragma unroll
    for (int q = 0; q < NQ; ++q) {
        float v2 = acc[q];
        v2 += __shfl_down(v2, 32);
        v2 += __shfl_down(v2, 16);
        v2 += __shfl_down(v2, 8);
        v2 += __shfl_down(v2, 4);
        v2 += __shfl_down(v2, 2);
        v2 += __shfl_down(v2, 1);
        acc[q] = v2;
    }
    const int wave = tid >> 6, lane = tid & 63;
    if (lane == 0) {
#pragma unroll
        for (int q = 0; q < NQ; ++q) red[wave][q] = acc[q];
    }
    __syncthreads();
    if (tid < NQ) {
        float v2 = 0.f;
#pragma unroll
        for (int w = 0; w < THREADS / 64; ++w) v2 += red[w][tid];
        out[b * NQ + tid] = v2;
    }
}

extern "C" void kernel_launch(void* const* d_in, const int* in_sizes, int n_in,
                              void* d_out, int out_size, void* d_ws, size_t ws_size,
                              hipStream_t stream) {
    const float* inputs  = (const float*)d_in[0];
    const float* weights = (const float*)d_in[1];
    float* out = (float*)d_out;
    const int B = in_sizes[0] / NQ;   // 256
    qsim_kernel<<<dim3(B), dim3(THREADS), 0, stream>>>(inputs, weights, out);
}